// Round 6
// baseline (334.021 us; speedup 1.0000x reference)
//
#include <hip/hip_runtime.h>
#include <hip/hip_fp16.h>

#define N_NODES 50000
#define N_EDGES 800000
#define D_FEAT  64
#define BSHIFT  6
#define NBKT    782               // ceil(50000/64)
#define PSHIFT  20
#define SRC_MASK ((1 << PSHIFT) - 1)   // src < 50000 < 2^20

// ---------- workspace layout (ints) ----------
#define WS_FLAG    0
#define WS_CC      64                        // coarse counts [NBKT]
#define WS_COFF    (WS_CC + NBKT)            // coarse offs [NBKT+1]
#define WS_CCUR    (WS_COFF + NBKT + 1)      // coarse cursors [NBKT]
#define WS_OFFS    (WS_CCUR + NBKT)          // per-node offs [N_NODES+1]
#define WS_PAIR    (WS_OFFS + N_NODES + 1)   // packed (src|dstlow<<20) [N_EDGES]
#define WS_SSRC    (WS_PAIR + N_EDGES)       // dst-sorted src [N_EDGES]
#define WS_PACKED  (WS_SSRC + N_EDGES)       // __half2[N_NODES*D_FEAT]
#define WS_INTS    (WS_PACKED + N_NODES * D_FEAT)

__device__ inline void detect_idx_layout(const int* idx, int* flag) {
    // indices < 50000: if stored as int64 LE, every odd 32-bit word is 0.
    int allzero = 1;
    #pragma unroll
    for (int i = 1; i < 129; i += 2) {
        if (idx[i] != 0) allzero = 0;
    }
    *flag = allzero;
}

// K0: zero coarse counts, detect layout, cast+interleave features to fp16
__global__ __launch_bounds__(256) void init_cast(int* __restrict__ W,
                                                 const int* __restrict__ idx,
                                                 const float* __restrict__ xs,
                                                 const float* __restrict__ xp) {
    int tid = blockIdx.x * blockDim.x + threadIdx.x;
    int stride = gridDim.x * blockDim.x;
    for (int i = tid; i < NBKT; i += stride) W[WS_CC + i] = 0;
    __half2* packed = (__half2*)(W + WS_PACKED);
    const int total = N_NODES * D_FEAT;
    for (int i = tid; i < total; i += stride)
        packed[i] = __floats2half2_rn(xs[i], xp[i]);
    if (tid == 0) {
        detect_idx_layout(idx, W + WS_FLAG);
        W[WS_OFFS + N_NODES] = N_EDGES;
    }
}

// K1: coarse histogram (dst>>6) with LDS privatization. 128 blocks.
__global__ __launch_bounds__(256) void coarse_hist(const int* __restrict__ idx,
                                                   int* __restrict__ W) {
    __shared__ int h[NBKT];
    for (int i = threadIdx.x; i < NBKT; i += 256) h[i] = 0;
    __syncthreads();
    const int flg = W[WS_FLAG];
    const int chunk = N_EDGES / 128;           // 6250
    const int base = blockIdx.x * chunk;
    for (int e = base + threadIdx.x; e < base + chunk; e += 256) {
        int dst = flg ? idx[2 * (N_EDGES + e)] : idx[N_EDGES + e];
        atomicAdd(&h[dst >> BSHIFT], 1);
    }
    __syncthreads();
    for (int i = threadIdx.x; i < NBKT; i += 256)
        if (h[i]) atomicAdd(&W[WS_CC + i], h[i]);
}

// K2: single-block scan of NBKT coarse counts -> coarse offs + cursors
__global__ __launch_bounds__(1024) void coarse_scan(int* __restrict__ W) {
    __shared__ int part[1024];
    int t = threadIdx.x;
    int v = (t < NBKT) ? W[WS_CC + t] : 0;
    part[t] = v;
    __syncthreads();
    for (int off = 1; off < 1024; off <<= 1) {
        int u = (t >= off) ? part[t - off] : 0;
        __syncthreads();
        part[t] += u;
        __syncthreads();
    }
    if (t < NBKT) {
        int excl = part[t] - v;
        W[WS_COFF + t] = excl;
        W[WS_CCUR + t] = excl;
    }
    if (t == 0) W[WS_COFF + NBKT] = N_EDGES;
}

// K3: coarse scatter — append (src|dstlow) into per-bucket sequential regions
__global__ __launch_bounds__(256) void coarse_scatter(const int* __restrict__ idx,
                                                      int* __restrict__ W) {
    int t = blockIdx.x * blockDim.x + threadIdx.x;
    if (t >= N_EDGES / 8) return;
    int e0 = 8 * t;
    const int flg = W[WS_FLAG];
    int s[8], d[8];
    if (flg) {
        #pragma unroll
        for (int k = 0; k < 8; k += 2) {
            int4 sv = *(const int4*)&idx[2 * (e0 + k)];
            int4 dv = *(const int4*)&idx[2 * (N_EDGES + e0 + k)];
            s[k] = sv.x; s[k + 1] = sv.z;
            d[k] = dv.x; d[k + 1] = dv.z;
        }
    } else {
        #pragma unroll
        for (int k = 0; k < 8; k += 4) {
            int4 sv = *(const int4*)&idx[e0 + k];
            int4 dv = *(const int4*)&idx[N_EDGES + e0 + k];
            s[k] = sv.x; s[k + 1] = sv.y; s[k + 2] = sv.z; s[k + 3] = sv.w;
            d[k] = dv.x; d[k + 1] = dv.y; d[k + 2] = dv.z; d[k + 3] = dv.w;
        }
    }
    int p[8];
    #pragma unroll
    for (int k = 0; k < 8; ++k)
        p[k] = atomicAdd(&W[WS_CCUR + (d[k] >> BSHIFT)], 1);
    #pragma unroll
    for (int k = 0; k < 8; ++k)
        W[WS_PAIR + p[k]] = s[k] | ((d[k] & 63) << PSHIFT);
}

// K4: per-bucket fine counting sort (LDS hist[64]) -> offs[node] + sorted ssrc
__global__ __launch_bounds__(256) void fine_sort(int* __restrict__ W) {
    __shared__ int h[64];
    int b = blockIdx.x;
    int t = threadIdx.x;
    int bbase = W[WS_COFF + b];
    int bend  = W[WS_COFF + b + 1];
    if (t < 64) h[t] = 0;
    __syncthreads();
    for (int e = bbase + t; e < bend; e += 256)
        atomicAdd(&h[(unsigned)W[WS_PAIR + e] >> PSHIFT], 1);
    __syncthreads();
    if (t < 64) {
        int c = h[t];
        int incl = c;
        #pragma unroll
        for (int off = 1; off < 64; off <<= 1) {
            int u = __shfl_up(incl, off, 64);
            if (t >= off) incl += u;
        }
        int excl = incl - c;
        int node = (b << BSHIFT) + t;
        if (node < N_NODES) W[WS_OFFS + node] = bbase + excl;
        h[t] = excl;   // becomes the local cursor
    }
    __syncthreads();
    for (int e = bbase + t; e < bend; e += 256) {
        int v = W[WS_PAIR + e];
        int p = atomicAdd(&h[(unsigned)v >> PSHIFT], 1);
        W[WS_SSRC + bbase + p] = v & SRC_MASK;
    }
}

// K5: one wave per node; lane = feature; fp16 interleaved gathers, fp32 accum
__global__ __launch_bounds__(256) void gather_reduce(const int* __restrict__ W,
                                                     float* __restrict__ out) {
    int wave = (int)((blockIdx.x * blockDim.x + threadIdx.x) >> 6);
    int lane = threadIdx.x & 63;
    if (wave >= N_NODES) return;
    int beg = W[WS_OFFS + wave];
    int end = W[WS_OFFS + wave + 1];
    const int* ssrc = W + WS_SSRC;
    const __half2* packed = (const __half2*)(W + WS_PACKED);

    float s0 = 0.f, s1 = 0.f, s2 = 0.f, s3 = 0.f;
    float p0 = 1.f, p1 = 1.f, p2 = 1.f, p3 = 1.f;
    int i = beg;
    for (; i + 3 < end; i += 4) {
        int a = ssrc[i], b = ssrc[i + 1], c = ssrc[i + 2], d = ssrc[i + 3];
        float2 fa = __half22float2(packed[a * D_FEAT + lane]);
        float2 fb = __half22float2(packed[b * D_FEAT + lane]);
        float2 fc = __half22float2(packed[c * D_FEAT + lane]);
        float2 fd = __half22float2(packed[d * D_FEAT + lane]);
        s0 += fa.x; s1 += fb.x; s2 += fc.x; s3 += fd.x;
        p0 *= fa.y; p1 *= fb.y; p2 *= fc.y; p3 *= fd.y;
    }
    for (; i < end; ++i) {
        float2 f = __half22float2(packed[ssrc[i] * D_FEAT + lane]);
        s0 += f.x;
        p0 *= f.y;
    }
    out[(long)wave * D_FEAT + lane] = (s0 + s1) + (s2 + s3);
    out[(long)N_NODES * D_FEAT + (long)wave * D_FEAT + lane] = (p0 * p1) * (p2 * p3);
}

// ---------------- fallback (atomic) path, used only if ws is too small ----------------
__device__ inline void atomicMulF32(float* addr, float val) {
    unsigned int* ua = (unsigned int*)addr;
    unsigned int old = __hip_atomic_load(ua, __ATOMIC_RELAXED, __HIP_MEMORY_SCOPE_AGENT);
    while (true) {
        unsigned int assumed = old;
        unsigned int desired = __float_as_uint(__uint_as_float(assumed) * val);
        old = atomicCAS(ua, assumed, desired);
        if (old == assumed) break;
    }
}

__global__ void fb_init(float* __restrict__ out, int* __restrict__ flag,
                        const int* __restrict__ idx) {
    const int n4 = (N_NODES * D_FEAT) / 4;
    int tid = blockIdx.x * blockDim.x + threadIdx.x;
    int stride = gridDim.x * blockDim.x;
    float4* o = (float4*)out;
    const float4 z = make_float4(0.f, 0.f, 0.f, 0.f);
    const float4 one = make_float4(1.f, 1.f, 1.f, 1.f);
    for (int i = tid; i < n4; i += stride) { o[i] = z; o[n4 + i] = one; }
    if (blockIdx.x == 0 && threadIdx.x == 0) detect_idx_layout(idx, flag);
}

__global__ void fb_scatter(const float* __restrict__ xs, const float* __restrict__ xp,
                           const int* __restrict__ idx, float* __restrict__ out,
                           const int* __restrict__ flag) {
    long tid = (long)blockIdx.x * blockDim.x + threadIdx.x;
    const long total = (long)N_EDGES * (D_FEAT / 4);
    if (tid >= total) return;
    int e = (int)(tid >> 4);
    int c = (int)(tid & 15);
    int src, dst;
    if (*flag) { src = idx[2 * e]; dst = idx[2 * (N_EDGES + e)]; }
    else       { src = idx[e];     dst = idx[N_EDGES + e]; }
    const float4 s = ((const float4*)(xs + (long)src * D_FEAT))[c];
    const float4 p = ((const float4*)(xp + (long)src * D_FEAT))[c];
    float* os = out + (long)dst * D_FEAT + c * 4;
    float* op = out + (long)N_NODES * D_FEAT + (long)dst * D_FEAT + c * 4;
    atomicAdd(os + 0, s.x); atomicAdd(os + 1, s.y);
    atomicAdd(os + 2, s.z); atomicAdd(os + 3, s.w);
    atomicMulF32(op + 0, p.x); atomicMulF32(op + 1, p.y);
    atomicMulF32(op + 2, p.z); atomicMulF32(op + 3, p.w);
}

extern "C" void kernel_launch(void* const* d_in, const int* in_sizes, int n_in,
                              void* d_out, int out_size, void* d_ws, size_t ws_size,
                              hipStream_t stream) {
    const float* x_sum  = (const float*)d_in[0];
    const float* x_prod = (const float*)d_in[1];
    const int*   eidx   = (const int*)d_in[2];
    float* out = (float*)d_out;
    int* W = (int*)d_ws;

    if (ws_size < (size_t)WS_INTS * sizeof(int)) {
        fb_init<<<1024, 256, 0, stream>>>(out, W, eidx);
        const long total = (long)N_EDGES * (D_FEAT / 4);
        int grid = (int)((total + 255) / 256);
        fb_scatter<<<grid, 256, 0, stream>>>(x_sum, x_prod, eidx, out, W);
        return;
    }

    init_cast<<<1024, 256, 0, stream>>>(W, eidx, x_sum, x_prod);
    coarse_hist<<<128, 256, 0, stream>>>(eidx, W);
    coarse_scan<<<1, 1024, 0, stream>>>(W);
    coarse_scatter<<<(N_EDGES / 8 + 255) / 256, 256, 0, stream>>>(eidx, W);
    fine_sort<<<NBKT, 256, 0, stream>>>(W);
    gather_reduce<<<(N_NODES + 3) / 4, 256, 0, stream>>>(W, out);
}